// Round 5
// baseline (4647.007 us; speedup 1.0000x reference)
//
#include <hip/hip_runtime.h>
#include <cstddef>
#include <cstring>

#define T_STEPS 512
#define BATCH   64
#define EDIM    512
#define HDIM    512
#define ODIM    512

#define HALF    256       // columns per scan block (2 blocks per cluster)

typedef __bf16 bf16;
typedef __bf16 bf16x8 __attribute__((ext_vector_type(8)));
typedef float  f32x4  __attribute__((ext_vector_type(4)));

union frag_u { unsigned long long u[2]; bf16x8 v; };
union bits_u { bf16 b; unsigned short s; };

// ---------------------------------------------------------------------------
// MFMA GEMM: C[r,n] = sum_k X[r*ldx+k] * W[n*ldw+kw0+k] + bias[n]
// 128x128 tile, BK=32, 256 threads = 4 waves (2x2 wave grid, 64x64 each).
// Fragment layouts proven on this HW (rounds 2/4):
//   A-frag: lane holds A[m=lane&15][k=(lane>>4)*8+j]
//   B-frag: lane holds B[k=(lane>>4)*8+j][n=lane&15]   (B = W^T)
//   D:      row=(lane>>4)*4+r, col=lane&15
// ---------------------------------------------------------------------------
template <typename XT>
__global__ __launch_bounds__(256) void gemm_mfma_kernel(
    const XT* __restrict__ X, int ldx,
    const float* __restrict__ W, int ldw, int kw0,
    const float* __restrict__ bias,
    float* __restrict__ C, int ldc, int K)
{
  __shared__ __align__(16) bf16 Asm[8 * 64 * 8];   // 8 KB: 8 mtiles
  __shared__ __align__(16) bf16 Bsm[8 * 64 * 8];   // 8 KB: 8 ntiles

  const int tid  = threadIdx.x;
  const int row0 = blockIdx.x * 128;
  const int col0 = blockIdx.y * 128;
  const int w    = tid >> 6, lane = tid & 63;
  const int q    = lane >> 4, nl = lane & 15;
  const int wm   = w >> 1, wn = w & 1;

  f32x4 acc[4][4] = {};

  for (int k0 = 0; k0 < K; k0 += 32) {
    // stage A tile (128 x 32) as frags
#pragma unroll
    for (int rep = 0; rep < 2; ++rep) {
      int idx = tid + rep * 256;
      int mt = idx >> 6, l2 = idx & 63;
      const XT* src = X + (size_t)(row0 + mt * 16 + (l2 & 15)) * ldx
                        + k0 + (l2 >> 4) * 8;
      bf16x8 v;
#pragma unroll
      for (int u = 0; u < 8; ++u) v[u] = (bf16)(float)src[u];
      *(bf16x8*)&Asm[(size_t)idx * 8] = v;
    }
    // stage B tile (W rows col0..col0+127, k slice) as frags
#pragma unroll
    for (int rep = 0; rep < 2; ++rep) {
      int idx = tid + rep * 256;
      int nt = idx >> 6, l2 = idx & 63;
      const float* src = W + (size_t)(col0 + nt * 16 + (l2 & 15)) * ldw
                           + kw0 + k0 + (l2 >> 4) * 8;
      bf16x8 v;
#pragma unroll
      for (int u = 0; u < 8; ++u) v[u] = (bf16)src[u];
      *(bf16x8*)&Bsm[(size_t)idx * 8] = v;
    }
    __syncthreads();

    bf16x8 a[4], b[4];
#pragma unroll
    for (int i = 0; i < 4; ++i)
      a[i] = *(bf16x8*)&Asm[(size_t)((wm * 4 + i) * 64 + lane) * 8];
#pragma unroll
    for (int j = 0; j < 4; ++j)
      b[j] = *(bf16x8*)&Bsm[(size_t)((wn * 4 + j) * 64 + lane) * 8];
#pragma unroll
    for (int i = 0; i < 4; ++i)
#pragma unroll
      for (int j = 0; j < 4; ++j)
        acc[i][j] = __builtin_amdgcn_mfma_f32_16x16x32_bf16(a[i], b[j], acc[i][j], 0, 0, 0);
    __syncthreads();
  }

#pragma unroll
  for (int i = 0; i < 4; ++i)
#pragma unroll
    for (int j = 0; j < 4; ++j) {
      int colg = col0 + wn * 64 + j * 16 + nl;
#pragma unroll
      for (int r = 0; r < 4; ++r) {
        size_t rowg = (size_t)(row0 + wm * 64 + i * 16 + q * 4 + r);
        C[rowg * ldc + colg] = acc[i][j][r] + bias[colg];
      }
    }
}

// ---------------------------------------------------------------------------
// Scan: 8 blocks x 512 threads. Block (c=bid>>1, s=bid&1): batch rows
// 16c..16c+15, cols s*256..s*256+255. W slice entirely in regs (128 VGPR).
// h exchanged via AGENT-scope relaxed atomics (sc0 sc1 -> Infinity Cache,
// always coherent) — NO threadfence / L2 writeback anywhere. Ordering:
// stores -> __syncthreads (drains vmcnt) -> tid0 flag add.
// ---------------------------------------------------------------------------
__global__ __launch_bounds__(512, 2) void scan_kernel(
    const float* __restrict__ A,     // [B*T, H] fp32, row = b*T + t
    const float* __restrict__ W1,    // [H, E+H] fp32
    bf16* __restrict__ Hbf,          // [B*T, H] bf16 (agent-coherent traffic)
    int* __restrict__ flags)         // 8 flags, 32-int stride
{
  const int tid  = threadIdx.x;
  const int bid  = blockIdx.x;
  const int c    = bid >> 1;
  const int s    = bid & 1;
  const int col0 = s * HALF;
  const int rb0  = c * 16;
  const int w    = tid >> 6, lane = tid & 63;
  const int q    = lane >> 4, nl = lane & 15;

  // ---- one-time: W slice kt 0..15, own 2 tiles -> 128 VGPRs --------------
  bf16x8 Wreg[2][16];
#pragma unroll
  for (int i = 0; i < 2; ++i) {
    int n = col0 + w * 32 + i * 16 + nl;
    const float* wrow = W1 + (size_t)n * (EDIM + HDIM) + EDIM;
#pragma unroll
    for (int kt = 0; kt < 16; ++kt) {
      const float* src = wrow + kt * 32 + q * 8;
      bf16x8 v;
#pragma unroll
      for (int u = 0; u < 8; ++u) v[u] = (bf16)src[u];
      Wreg[i][kt] = v;
    }
  }

  int* myflag = flags + (c * 2 + s) * 32;
  int* paflag = flags + (c * 2 + (1 - s)) * 32;

  // ---- A prefetch (fp32) -------------------------------------------------
  float Ac[2][4], An[2][4];
#pragma unroll
  for (int i = 0; i < 2; ++i)
#pragma unroll
    for (int r = 0; r < 4; ++r)
      Ac[i][r] = A[((size_t)(rb0 + q * 4 + r) * T_STEPS + 0) * HDIM
                   + col0 + w * 32 + i * 16 + nl];

  f32x4 acc[2];

  for (int t = 0; t < T_STEPS; ++t) {
    if (t > 0) {
      // wait for partner h_{t-1} (relaxed agent poll; no fences needed —
      // the data stores below are themselves agent-coherent)
      if (tid == 0) {
        while (__hip_atomic_load(paflag, __ATOMIC_RELAXED,
                                 __HIP_MEMORY_SCOPE_AGENT) < t) {}
      }
      __syncthreads();
    }

#pragma unroll
    for (int i = 0; i < 2; ++i)
#pragma unroll
      for (int r = 0; r < 4; ++r) acc[i][r] = Ac[i][r];

    // prefetch A_{t+1}
    {
      int tn = (t + 1 < T_STEPS) ? t + 1 : 0;
#pragma unroll
      for (int i = 0; i < 2; ++i)
#pragma unroll
        for (int r = 0; r < 4; ++r)
          An[i][r] = A[((size_t)(rb0 + q * 4 + r) * T_STEPS + tn) * HDIM
                       + col0 + w * 32 + i * 16 + nl];
    }

    // ---- h_{t-1} @ W1h^T, full K=512, A-frags from coherent global -------
    if (t > 0) {
      const bf16* hrow = Hbf + ((size_t)(rb0 + nl) * T_STEPS + (t - 1)) * HDIM;
#pragma unroll
      for (int kt = 0; kt < 16; ++kt) {
        const unsigned long long* p =
            (const unsigned long long*)(hrow + kt * 32 + q * 8);
        frag_u f;
        f.u[0] = __hip_atomic_load(p,     __ATOMIC_RELAXED, __HIP_MEMORY_SCOPE_AGENT);
        f.u[1] = __hip_atomic_load(p + 1, __ATOMIC_RELAXED, __HIP_MEMORY_SCOPE_AGENT);
#pragma unroll
        for (int i = 0; i < 2; ++i)
          acc[i] = __builtin_amdgcn_mfma_f32_16x16x32_bf16(f.v, Wreg[i][kt], acc[i], 0, 0, 0);
      }
    }

    // ---- relu + store own h_t half (agent-coherent shorts) ---------------
#pragma unroll
    for (int i = 0; i < 2; ++i)
#pragma unroll
      for (int r = 0; r < 4; ++r) {
        float v = acc[i][r] > 0.0f ? acc[i][r] : 0.0f;
        int colg = col0 + w * 32 + i * 16 + nl;
        bits_u bu; bu.b = (bf16)v;
        __hip_atomic_store(
            (unsigned short*)(Hbf + ((size_t)(rb0 + q * 4 + r) * T_STEPS + t) * HDIM + colg),
            bu.s, __ATOMIC_RELAXED, __HIP_MEMORY_SCOPE_AGENT);
      }

    // rotate A prefetch
#pragma unroll
    for (int i = 0; i < 2; ++i)
#pragma unroll
      for (int r = 0; r < 4; ++r) Ac[i][r] = An[i][r];

    __syncthreads();   // drains every wave's vmcnt -> h_t globally visible
    if (tid == 0)
      __hip_atomic_fetch_add(myflag, 1, __ATOMIC_RELAXED,
                             __HIP_MEMORY_SCOPE_AGENT);
  }
}

// ---------------------------------------------------------------------------
// h_final = Hbf[:, T-1, :] -> fp32 tail of d_out
// ---------------------------------------------------------------------------
__global__ __launch_bounds__(256) void copy_hfinal_kernel(
    const bf16* __restrict__ Hbf, float* __restrict__ out)
{
  int i = blockIdx.x * blockDim.x + threadIdx.x;   // 0 .. B*H-1
  int b = i / HDIM, n = i % HDIM;
  out[i] = (float)Hbf[((size_t)b * T_STEPS + (T_STEPS - 1)) * HDIM + n];
}

extern "C" void kernel_launch(void* const* d_in, const int* in_sizes, int n_in,
                              void* d_out, int out_size, void* d_ws, size_t ws_size,
                              hipStream_t stream) {
  const float* x  = (const float*)d_in[0];   // [B, T, E]
  const float* W1 = (const float*)d_in[1];   // [H, E+H]
  const float* b1 = (const float*)d_in[2];   // [H]
  const float* W2 = (const float*)d_in[3];   // [O, H]
  const float* b2 = (const float*)d_in[4];   // [O]

  float* out = (float*)d_out;
  float* A   = out;   // fp32 x-projection staged in d_out; consumed by scan
                      // before the output GEMM overwrites it

  bf16* Hbf  = (bf16*)d_ws;                                       // 32 MB
  int* flags = (int*)((char*)d_ws + (size_t)BATCH * T_STEPS * HDIM * 2);

  // 0) zero the flags (ws is poisoned 0xAA each launch)
  hipMemsetAsync(flags, 0, 8 * 32 * sizeof(int), stream);

  // 1) A = X @ W1[:, :E]^T + b1  (bf16 MFMA, fp32 accumulate/out)
  {
    dim3 grid(BATCH * T_STEPS / 128, HDIM / 128);
    gemm_mfma_kernel<float><<<grid, 256, 0, stream>>>(
        x, EDIM, W1, EDIM + HDIM, /*kw0=*/0, b1, A, HDIM, EDIM);
  }

  // 2) scan: h_t = relu(A_t + h_{t-1} @ W1[:, E:]^T), 2 blocks per cluster
  scan_kernel<<<8, 512, 0, stream>>>(A, W1, Hbf, flags);

  // 3) outs = Hbf @ W2^T + b2 (overwrites the A staging area)
  {
    dim3 grid(BATCH * T_STEPS / 128, ODIM / 128);
    gemm_mfma_kernel<bf16><<<grid, 256, 0, stream>>>(
        Hbf, HDIM, W2, HDIM, /*kw0=*/0, b2, out, ODIM, HDIM);
  }

  // 4) h_final tail
  copy_hfinal_kernel<<<(BATCH * HDIM) / 256, 256, 0, stream>>>(
      Hbf, out + (size_t)BATCH * T_STEPS * ODIM);
}

// Round 6
// 1396.943 us; speedup vs baseline: 3.3266x; 3.3266x over previous
//
#include <hip/hip_runtime.h>
#include <cstddef>

#define T_STEPS 512
#define BATCH   64
#define EDIM    512
#define HDIM    512
#define ODIM    512

#define HPAD    520                // hsm row stride (bf16): 16B-aligned, 2-way banks (free)
#define W_ELEMS (32 * 4 * 64 * 8)  // W kt 0..3: 131072 B
#define H_ELEMS (16 * HPAD)        // 16640 B
#define SMEM_BYTES ((W_ELEMS + H_ELEMS) * 2)   // 147712

typedef __bf16 bf16;
typedef __bf16 bf16x8 __attribute__((ext_vector_type(8)));
typedef float  f32x4  __attribute__((ext_vector_type(4)));

// ---------------------------------------------------------------------------
// MFMA GEMM (round-5 proven): C[r,n] = sum_k X[r,k] * W[n, kw0+k] + bias[n]
// 128x128 tile, BK=32, 4 waves. Frag layouts proven r2/r4/r5.
// ---------------------------------------------------------------------------
template <typename XT>
__global__ __launch_bounds__(256) void gemm_mfma_kernel(
    const XT* __restrict__ X, int ldx,
    const float* __restrict__ W, int ldw, int kw0,
    const float* __restrict__ bias,
    float* __restrict__ C, int ldc, int K)
{
  __shared__ __align__(16) bf16 Asm[8 * 64 * 8];
  __shared__ __align__(16) bf16 Bsm[8 * 64 * 8];

  const int tid  = threadIdx.x;
  const int row0 = blockIdx.x * 128;
  const int col0 = blockIdx.y * 128;
  const int w    = tid >> 6, lane = tid & 63;
  const int q    = lane >> 4, nl = lane & 15;
  const int wm   = w >> 1, wn = w & 1;

  f32x4 acc[4][4] = {};

  for (int k0 = 0; k0 < K; k0 += 32) {
#pragma unroll
    for (int rep = 0; rep < 2; ++rep) {
      int idx = tid + rep * 256;
      int mt = idx >> 6, l2 = idx & 63;
      const XT* src = X + (size_t)(row0 + mt * 16 + (l2 & 15)) * ldx
                        + k0 + (l2 >> 4) * 8;
      bf16x8 v;
#pragma unroll
      for (int u = 0; u < 8; ++u) v[u] = (bf16)(float)src[u];
      *(bf16x8*)&Asm[(size_t)idx * 8] = v;
    }
#pragma unroll
    for (int rep = 0; rep < 2; ++rep) {
      int idx = tid + rep * 256;
      int nt = idx >> 6, l2 = idx & 63;
      const float* src = W + (size_t)(col0 + nt * 16 + (l2 & 15)) * ldw
                           + kw0 + k0 + (l2 >> 4) * 8;
      bf16x8 v;
#pragma unroll
      for (int u = 0; u < 8; ++u) v[u] = (bf16)src[u];
      *(bf16x8*)&Bsm[(size_t)idx * 8] = v;
    }
    __syncthreads();

    bf16x8 a[4], b[4];
#pragma unroll
    for (int i = 0; i < 4; ++i)
      a[i] = *(bf16x8*)&Asm[(size_t)((wm * 4 + i) * 64 + lane) * 8];
#pragma unroll
    for (int j = 0; j < 4; ++j)
      b[j] = *(bf16x8*)&Bsm[(size_t)((wn * 4 + j) * 64 + lane) * 8];
#pragma unroll
    for (int i = 0; i < 4; ++i)
#pragma unroll
      for (int j = 0; j < 4; ++j)
        acc[i][j] = __builtin_amdgcn_mfma_f32_16x16x32_bf16(a[i], b[j], acc[i][j], 0, 0, 0);
    __syncthreads();
  }

#pragma unroll
  for (int i = 0; i < 4; ++i)
#pragma unroll
    for (int j = 0; j < 4; ++j) {
      int colg = col0 + wn * 64 + j * 16 + nl;
#pragma unroll
      for (int r = 0; r < 4; ++r) {
        size_t rowg = (size_t)(row0 + wm * 64 + i * 16 + q * 4 + r);
        C[rowg * ldc + colg] = acc[i][j][r] + bias[colg];
      }
    }
}

// ---------------------------------------------------------------------------
// BIG scan: 4 workgroups x 512 threads (8 waves), one per cluster of 16
// batch rows; ALL 512 cols -> recurrence closes with __syncthreads only.
// Dynamic LDS 147,712 B: W1h kt 0..3 (128 KB, frag-swizzled) + hsm (16.6 KB).
// W1h kt 4..15 in 192 VGPRs/lane (wave w owns n-tiles w*4+i, i=0..3).
// A read fp32 directly (proven r4/r5 pattern), prefetched one step ahead.
// Frag layouts proven r2/r4/r5:
//   A-frag: lane holds A[m=lane&15][k=(lane>>4)*8+j]
//   B-frag: lane holds B[k=(lane>>4)*8+j][n=lane&15]  (B = W1h^T)
//   D:      row=(lane>>4)*4+r, col=lane&15
// ---------------------------------------------------------------------------
__global__ __launch_bounds__(512, 2) void scan_big_kernel(
    const float* __restrict__ A,     // [B*T, H] fp32, row = b*T + t
    const float* __restrict__ W1,    // [H, E+H] fp32
    bf16* __restrict__ Hbf)          // [B*T, H] bf16
{
  extern __shared__ __align__(16) bf16 smem[];
  bf16* Wlds = smem;                 // [tg(32)][kt(4)][lane(64)][8]
  bf16* hsm  = smem + W_ELEMS;       // [16][HPAD]

  const int tid  = threadIdx.x;
  const int c    = blockIdx.x;
  const int w    = tid >> 6, lane = tid & 63;
  const int q    = lane >> 4, nl = lane & 15;
  const int rb0  = c * 16;

  // ---- one-time: W kt 0..3, all 32 n-tiles -> LDS ------------------------
  for (int idx = tid; idx < 32 * 4 * 64; idx += 512) {
    int l  = idx & 63;
    int kt = (idx >> 6) & 3;
    int tg = idx >> 8;
    int n  = tg * 16 + (l & 15);
    int k  = kt * 32 + (l >> 4) * 8;
    const float* src = W1 + (size_t)n * (EDIM + HDIM) + EDIM + k;
    bf16x8 v;
#pragma unroll
    for (int u = 0; u < 8; ++u) v[u] = (bf16)src[u];
    *(bf16x8*)&Wlds[(size_t)idx * 8] = v;
  }

  // ---- one-time: W kt 4..15 for this wave's 4 tiles -> 192 VGPRs ---------
  bf16x8 Wreg[4][12];
#pragma unroll
  for (int i = 0; i < 4; ++i) {
    int n = w * 64 + i * 16 + nl;
    const float* wrow = W1 + (size_t)n * (EDIM + HDIM) + EDIM;
#pragma unroll
    for (int kt2 = 0; kt2 < 12; ++kt2) {
      const float* src = wrow + (kt2 + 4) * 32 + q * 8;
      bf16x8 v;
#pragma unroll
      for (int u = 0; u < 8; ++u) v[u] = (bf16)src[u];
      Wreg[i][kt2] = v;
    }
  }
  __syncthreads();

  // ---- prefetch A_0 (fp32, 16 scalar loads) ------------------------------
  float An[4][4];
#pragma unroll
  for (int i = 0; i < 4; ++i)
#pragma unroll
    for (int r = 0; r < 4; ++r)
      An[i][r] = A[((size_t)(rb0 + q * 4 + r) * T_STEPS + 0) * HDIM
                   + w * 64 + i * 16 + nl];

  f32x4 acc[4];

  for (int t = 0; t < T_STEPS; ++t) {
    // ---- stream out h_{t-1} (reads hsm; same phase as MFMA hsm reads) ----
    if (t > 0) {
      int m = tid >> 5, j = tid & 31;          // row m, elems 16j..16j+15
      bf16x8 h0 = *(bf16x8*)&hsm[m * HPAD + j * 16];
      bf16x8 h1 = *(bf16x8*)&hsm[m * HPAD + j * 16 + 8];
      bf16* dst = Hbf + ((size_t)(rb0 + m) * T_STEPS + (t - 1)) * HDIM + j * 16;
      *(bf16x8*)dst       = h0;
      *(bf16x8*)(dst + 8) = h1;
    }

    // ---- acc init from prefetched A_t ------------------------------------
#pragma unroll
    for (int i = 0; i < 4; ++i)
#pragma unroll
      for (int r = 0; r < 4; ++r) acc[i][r] = An[i][r];

    // ---- issue A_{t+1} prefetch ------------------------------------------
    {
      int tn = (t + 1 < T_STEPS) ? t + 1 : 0;
#pragma unroll
      for (int i = 0; i < 4; ++i)
#pragma unroll
        for (int r = 0; r < 4; ++r)
          An[i][r] = A[((size_t)(rb0 + q * 4 + r) * T_STEPS + tn) * HDIM
                       + w * 64 + i * 16 + nl];
    }

    // ---- h_{t-1} @ W1h^T over full K=512 ---------------------------------
    if (t > 0) {
#pragma unroll
      for (int kt = 0; kt < 16; ++kt) {
        bf16x8 af = *(bf16x8*)&hsm[nl * HPAD + kt * 32 + q * 8];
        if (kt < 4) {
#pragma unroll
          for (int i = 0; i < 4; ++i) {
            bf16x8 b = *(bf16x8*)&Wlds[(size_t)(((w * 4 + i) * 4 + kt) * 64 + lane) * 8];
            acc[i] = __builtin_amdgcn_mfma_f32_16x16x32_bf16(af, b, acc[i], 0, 0, 0);
          }
        } else {
#pragma unroll
          for (int i = 0; i < 4; ++i)
            acc[i] = __builtin_amdgcn_mfma_f32_16x16x32_bf16(af, Wreg[i][kt - 4], acc[i], 0, 0, 0);
        }
      }
    }

    __syncthreads();   // all hsm reads of h_{t-1} done

    // ---- relu + write h_t to hsm -----------------------------------------
#pragma unroll
    for (int i = 0; i < 4; ++i)
#pragma unroll
      for (int r = 0; r < 4; ++r) {
        float v = acc[i][r] > 0.0f ? acc[i][r] : 0.0f;
        hsm[(q * 4 + r) * HPAD + w * 64 + i * 16 + nl] = (bf16)v;
      }

    __syncthreads();   // h_t visible to all waves
  }

  // ---- epilogue: stream out h_{T-1} --------------------------------------
  {
    int m = tid >> 5, j = tid & 31;
    bf16x8 h0 = *(bf16x8*)&hsm[m * HPAD + j * 16];
    bf16x8 h1 = *(bf16x8*)&hsm[m * HPAD + j * 16 + 8];
    bf16* dst = Hbf + ((size_t)(rb0 + m) * T_STEPS + (T_STEPS - 1)) * HDIM + j * 16;
    *(bf16x8*)dst       = h0;
    *(bf16x8*)(dst + 8) = h1;
  }
}

// ---------------------------------------------------------------------------
// FALLBACK scan (round-4 verbatim, proven pass): 8 blocks, fence protocol.
// ---------------------------------------------------------------------------
#define HALF 256
__global__ __launch_bounds__(512) void scan_fallback_kernel(
    const float* __restrict__ A,
    const float* __restrict__ W1,
    bf16* __restrict__ Hbf,
    int* __restrict__ flags)
{
  __shared__ __align__(16) bf16 WldsF[16 * 2 * 64 * 8];
  __shared__ __align__(16) bf16 hsmF[16 * HPAD];

  const int tid   = threadIdx.x;
  const int bid   = blockIdx.x;
  const int c     = bid >> 1;
  const int s     = bid & 1;
  const int col0  = s * HALF;
  const int pcol0 = (1 - s) * HALF;
  const int rb0   = c * 16;
  const int w     = tid >> 6, lane = tid & 63;
  const int q     = lane >> 4, nl = lane & 15;

  for (int idx = tid; idx < 16 * 2 * 64; idx += 512) {
    int l  = idx & 63;
    int kt = (idx >> 6) & 1;
    int tg = idx >> 7;
    int n  = col0 + tg * 16 + (l & 15);
    int k  = kt * 32 + (l >> 4) * 8;
    const float* src = W1 + (size_t)n * (EDIM + HDIM) + EDIM + k;
    bf16x8 v;
#pragma unroll
    for (int u = 0; u < 8; ++u) v[u] = (bf16)src[u];
    *(bf16x8*)&WldsF[(size_t)idx * 8] = v;
  }

  bf16x8 Wreg[2][14];
#pragma unroll
  for (int i = 0; i < 2; ++i) {
    int n = col0 + w * 32 + i * 16 + nl;
    const float* wrow = W1 + (size_t)n * (EDIM + HDIM) + EDIM;
#pragma unroll
    for (int kt2 = 0; kt2 < 14; ++kt2) {
      const float* src = wrow + (kt2 + 2) * 32 + q * 8;
      bf16x8 v;
#pragma unroll
      for (int u = 0; u < 8; ++u) v[u] = (bf16)src[u];
      Wreg[i][kt2] = v;
    }
  }
  __syncthreads();

  int* myflag = flags + (c * 2 + s) * 32;
  int* paflag = flags + (c * 2 + (1 - s)) * 32;

  float Ac[2][4], An[2][4];
#pragma unroll
  for (int i = 0; i < 2; ++i)
#pragma unroll
    for (int r = 0; r < 4; ++r)
      Ac[i][r] = A[((size_t)(rb0 + q * 4 + r) * T_STEPS + 0) * HDIM
                   + col0 + w * 32 + i * 16 + nl];

  f32x4 acc[2];

  for (int t = 0; t < T_STEPS; ++t) {
    if (t > 0) {
      if (tid == 0) {
        while (__hip_atomic_load(paflag, __ATOMIC_RELAXED,
                                 __HIP_MEMORY_SCOPE_AGENT) < t) {}
      }
      __syncthreads();
      __threadfence();
      int m = tid >> 5, j = tid & 31;
      bf16x8 hv = *(const bf16x8*)(
          Hbf + ((size_t)(rb0 + m) * T_STEPS + (t - 1)) * HDIM + pcol0 + j * 8);
      *(bf16x8*)&hsmF[m * HPAD + pcol0 + j * 8] = hv;
    }

#pragma unroll
    for (int i = 0; i < 2; ++i)
#pragma unroll
      for (int r = 0; r < 4; ++r) acc[i][r] = Ac[i][r];

    {
      int tn = (t + 1 < T_STEPS) ? t + 1 : 0;
#pragma unroll
      for (int i = 0; i < 2; ++i)
#pragma unroll
        for (int r = 0; r < 4; ++r)
          An[i][r] = A[((size_t)(rb0 + q * 4 + r) * T_STEPS + tn) * HDIM
                       + col0 + w * 32 + i * 16 + nl];
    }

    if (t > 0) {
      __syncthreads();
#pragma unroll
      for (int kt = 0; kt < 16; ++kt) {
        bf16x8 af = *(bf16x8*)&hsmF[nl * HPAD + kt * 32 + q * 8];
        if (kt < 2) {
#pragma unroll
          for (int i = 0; i < 2; ++i) {
            bf16x8 b = *(bf16x8*)&WldsF[(size_t)(((w * 2 + i) * 2 + kt) * 64 + lane) * 8];
            acc[i] = __builtin_amdgcn_mfma_f32_16x16x32_bf16(af, b, acc[i], 0, 0, 0);
          }
        } else {
#pragma unroll
          for (int i = 0; i < 2; ++i)
            acc[i] = __builtin_amdgcn_mfma_f32_16x16x32_bf16(af, Wreg[i][kt - 2], acc[i], 0, 0, 0);
        }
      }
    }

    __syncthreads();

#pragma unroll
    for (int i = 0; i < 2; ++i)
#pragma unroll
      for (int r = 0; r < 4; ++r) {
        float v = acc[i][r] > 0.0f ? acc[i][r] : 0.0f;
        int colg = col0 + w * 32 + i * 16 + nl;
        hsmF[(q * 4 + r) * HPAD + colg] = (bf16)v;
        Hbf[((size_t)(rb0 + q * 4 + r) * T_STEPS + t) * HDIM + colg] = (bf16)v;
      }

#pragma unroll
    for (int i = 0; i < 2; ++i)
#pragma unroll
      for (int r = 0; r < 4; ++r) Ac[i][r] = An[i][r];

    __syncthreads();
    if (tid == 0) {
      __threadfence();
      __hip_atomic_fetch_add(myflag, 1, __ATOMIC_RELAXED,
                             __HIP_MEMORY_SCOPE_AGENT);
    }
  }
}

// ---------------------------------------------------------------------------
__global__ __launch_bounds__(256) void copy_hfinal_kernel(
    const bf16* __restrict__ Hbf, float* __restrict__ out)
{
  int i = blockIdx.x * blockDim.x + threadIdx.x;
  int b = i / HDIM, n = i % HDIM;
  out[i] = (float)Hbf[((size_t)b * T_STEPS + (T_STEPS - 1)) * HDIM + n];
}

extern "C" void kernel_launch(void* const* d_in, const int* in_sizes, int n_in,
                              void* d_out, int out_size, void* d_ws, size_t ws_size,
                              hipStream_t stream) {
  const float* x  = (const float*)d_in[0];
  const float* W1 = (const float*)d_in[1];
  const float* b1 = (const float*)d_in[2];
  const float* W2 = (const float*)d_in[3];
  const float* b2 = (const float*)d_in[4];

  float* out = (float*)d_out;
  float* A   = out;   // fp32 x-projection staged in d_out; consumed by scan
                      // before the output GEMM overwrites it

  bf16* Hbf  = (bf16*)d_ws;                                       // 32 MB
  int* flags = (int*)((char*)d_ws + (size_t)BATCH * T_STEPS * HDIM * 2);

  hipMemsetAsync(flags, 0, 8 * 32 * sizeof(int), stream);

  // 1) A = X @ W1[:, :E]^T + b1  (bf16 MFMA, fp32 out)
  {
    dim3 grid(BATCH * T_STEPS / 128, HDIM / 128);
    gemm_mfma_kernel<float><<<grid, 256, 0, stream>>>(
        x, EDIM, W1, EDIM + HDIM, 0, b1, A, HDIM, EDIM);
  }

  // 2) scan. Preferred: single-workgroup-per-cluster with 147.7 KB dynamic
  // LDS (needs the opt-in attribute). Deterministic host-side fallback to
  // the proven round-4 kernel if the attribute isn't granted.
  hipError_t e = hipFuncSetAttribute(
      reinterpret_cast<const void*>(scan_big_kernel),
      hipFuncAttributeMaxDynamicSharedMemorySize, SMEM_BYTES);
  if (e == hipSuccess) {
    scan_big_kernel<<<4, 512, SMEM_BYTES, stream>>>(A, W1, Hbf);
  } else {
    scan_fallback_kernel<<<8, 512, 0, stream>>>(A, W1, Hbf, flags);
  }

  // 3) outs = Hbf @ W2^T + b2 (overwrites the A staging area)
  {
    dim3 grid(BATCH * T_STEPS / 128, ODIM / 128);
    gemm_mfma_kernel<bf16><<<grid, 256, 0, stream>>>(
        Hbf, HDIM, W2, HDIM, 0, b2, out, ODIM, HDIM);
  }

  // 4) h_final tail
  copy_hfinal_kernel<<<(BATCH * HDIM) / 256, 256, 0, stream>>>(
      Hbf, out + (size_t)BATCH * T_STEPS * ODIM);
}